// Round 1
// baseline (3986.697 us; speedup 1.0000x reference)
//
#include <hip/hip_runtime.h>
#include <hip/hip_fp16.h>
#include <stdint.h>

// Problem constants
#define BB   512
#define TT   1024
#define NIN  64
#define HH   128
#define GG   384      // 3*H
#define NFC  128
#define RPB  2        // batch rows per workgroup
#define NWG  (BB / RPB)   // 256 workgroups
#define NTHR (2 * GG)     // 768 threads: [0,384) layer0 gates, [384,768) layer1 gates

typedef _Float16 half2v __attribute__((ext_vector_type(2)));

__device__ __forceinline__ float fdot2(uint32_t a, uint32_t b, float c) {
    return __builtin_amdgcn_fdot2(__builtin_bit_cast(half2v, a),
                                  __builtin_bit_cast(half2v, b), c, false);
}
__device__ __forceinline__ uint32_t pack2(float a, float b) {
    half2v v; v[0] = (_Float16)a; v[1] = (_Float16)b;
    return __builtin_bit_cast(uint32_t, v);
}
__device__ __forceinline__ float sigm(float xv)  { return 1.f / (1.f + __expf(-xv)); }
__device__ __forceinline__ float tanhfast(float xv) { return 2.f / (1.f + __expf(-2.f * xv)) - 1.f; }

__global__ __launch_bounds__(NTHR, 3) void gru_fused(
    const float* __restrict__ x,
    const float* __restrict__ Wih0, const float* __restrict__ Whh0,
    const float* __restrict__ bih0, const float* __restrict__ bhh0,
    const float* __restrict__ Wih1, const float* __restrict__ Whh1,
    const float* __restrict__ bih1, const float* __restrict__ bhh1,
    const float* __restrict__ fc1w, const float* __restrict__ fc1b,
    const float* __restrict__ fc2w, const float* __restrict__ fc2b,
    float* __restrict__ out)
{
    // LDS: fp16x2-packed state for dot2 reads (broadcast), fp32 state for exact z*h,
    // pre-activation exchange buffers.
    __shared__ uint32_t xh[RPB][NIN / 2];     // x_t as fp16x2
    __shared__ uint32_t h0h[RPB][HH / 2];     // layer0 h as fp16x2
    __shared__ uint32_t h1h[RPB][HH / 2];     // layer1 h as fp16x2
    __shared__ float    h0f[RPB][HH];         // layer0 h fp32
    __shared__ float    h1f[RPB][HH];         // layer1 h fp32
    __shared__ float    pX0[RPB][GG], pH0[RPB][GG];   // layer0 pre-acts (x-part, h-part)
    __shared__ float    pX1[RPB][GG], pH1[RPB][GG];   // layer1 pre-acts

    const int lid  = threadIdx.x;
    const int row0 = blockIdx.x * RPB;
    const bool is0 = (lid < GG);

    // Per-thread register-resident weights (fp16x2 packed).
    // layer0 thread (gate g): wA[0:64] = W_hh0[g,0:128], wB[0:32] = W_ih0[g,0:64]
    // layer1 thread (gate g): wA[0:64] = W_hh1[g,0:128], wB[0:64] = W_ih1[g,0:128]
    uint32_t wA[HH / 2];
    uint32_t wB[HH / 2];
    float bx = 0.f, bh = 0.f;

    if (is0) {
        const int g = lid;
        const float* wi = Wih0 + g * NIN;
        #pragma unroll
        for (int k = 0; k < NIN / 2; ++k) wB[k] = pack2(wi[2 * k], wi[2 * k + 1]);
        const float* wh = Whh0 + g * HH;
        #pragma unroll
        for (int k = 0; k < HH / 2; ++k) wA[k] = pack2(wh[2 * k], wh[2 * k + 1]);
        bx = bih0[g]; bh = bhh0[g];
    } else {
        const int g = lid - GG;
        const float* wi = Wih1 + g * HH;
        #pragma unroll
        for (int k = 0; k < HH / 2; ++k) wB[k] = pack2(wi[2 * k], wi[2 * k + 1]);
        const float* wh = Whh1 + g * HH;
        #pragma unroll
        for (int k = 0; k < HH / 2; ++k) wA[k] = pack2(wh[2 * k], wh[2 * k + 1]);
        bx = bih1[g]; bh = bhh1[g];
    }

    // Zero-init hidden states.
    if (lid < 2 * HH) {
        int r = lid >> 7, j = lid & (HH - 1);
        h0f[r][j] = 0.f; h1f[r][j] = 0.f;
    } else if (lid < 2 * HH + 2 * (HH / 2)) {
        int k2 = lid - 2 * HH;          // [0,128)
        int r = k2 >> 6, c = k2 & 63;
        h0h[r][c] = 0u; h1h[r][c] = 0u;
    }

    // x staging threads: lids [GG+256, GG+384). Stage x_0 now, prefetch x_1 into reg.
    float xreg = 0.f;
    if (lid >= GG + 2 * HH) {
        int j2 = lid - (GG + 2 * HH);   // [0,128)
        int r = j2 >> 6, k = j2 & 63;
        const float* xp = x + (size_t)(row0 + r) * TT * NIN + k;
        ((__half*)&xh[r][0])[k] = __float2half(xp[0]);   // t = 0
        xreg = xp[NIN];                                   // t = 1
    }
    __syncthreads();

    // Main loop. Iteration i: layer0 computes step i (i < TT);
    // layer1 computes step i-1 (i >= 1). Layer1 lags one step -> both run concurrently.
    for (int i = 0; i <= TT; ++i) {
        // ---------------- phase 1: dot products ----------------
        if (is0) {
            if (i < TT) {
                float ax0 = bx, ax1 = bx, ah0 = bh, ah1 = bh;
                #pragma unroll
                for (int k = 0; k < NIN / 2; ++k) {
                    ax0 = fdot2(wB[k], xh[0][k], ax0);
                    ax1 = fdot2(wB[k], xh[1][k], ax1);
                }
                #pragma unroll
                for (int k = 0; k < HH / 2; ++k) {
                    ah0 = fdot2(wA[k], h0h[0][k], ah0);
                    ah1 = fdot2(wA[k], h0h[1][k], ah1);
                }
                pX0[0][lid] = ax0; pX0[1][lid] = ax1;
                pH0[0][lid] = ah0; pH0[1][lid] = ah1;
            }
        } else {
            if (i >= 1) {
                const int g = lid - GG;
                float ax0 = bx, ax1 = bx, ah0 = bh, ah1 = bh;
                #pragma unroll
                for (int k = 0; k < HH / 2; ++k) {
                    ax0 = fdot2(wB[k], h0h[0][k], ax0);
                    ax1 = fdot2(wB[k], h0h[1][k], ax1);
                    ah0 = fdot2(wA[k], h1h[0][k], ah0);
                    ah1 = fdot2(wA[k], h1h[1][k], ah1);
                }
                pX1[0][g] = ax0; pX1[1][g] = ax1;
                pH1[0][g] = ah0; pH1[1][g] = ah1;
            }
        }
        __syncthreads();

        // ---------------- phase 2: gate combine + x staging ----------------
        if (lid < 2 * HH) {                         // layer0 combine (256 threads)
            if (i < TT) {
                int r = lid >> 7, j = lid & (HH - 1);
                float sr = pX0[r][j]          + pH0[r][j];
                float sz = pX0[r][HH + j]     + pH0[r][HH + j];
                float xn = pX0[r][2 * HH + j];
                float hn = pH0[r][2 * HH + j];
                float rg = sigm(sr);
                float zg = sigm(sz);
                float ng = tanhfast(fmaf(rg, hn, xn));
                float hnew = fmaf(zg, h0f[r][j] - ng, ng);   // n + z*(h-n)
                h0f[r][j] = hnew;
                ((__half*)&h0h[r][0])[j] = __float2half(hnew);
            }
        } else if (lid >= GG && lid < GG + 2 * HH) { // layer1 combine (256 threads)
            if (i >= 1) {
                int t2 = lid - GG;
                int r = t2 >> 7, j = t2 & (HH - 1);
                float sr = pX1[r][j]          + pH1[r][j];
                float sz = pX1[r][HH + j]     + pH1[r][HH + j];
                float xn = pX1[r][2 * HH + j];
                float hn = pH1[r][2 * HH + j];
                float rg = sigm(sr);
                float zg = sigm(sz);
                float ng = tanhfast(fmaf(rg, hn, xn));
                float hnew = fmaf(zg, h1f[r][j] - ng, ng);
                h1f[r][j] = hnew;
                ((__half*)&h1h[r][0])[j] = __float2half(hnew);
            }
        } else if (lid >= GG + 2 * HH) {             // x staging (128 threads)
            int j2 = lid - (GG + 2 * HH);
            int r = j2 >> 6, k = j2 & 63;
            if (i + 1 < TT) ((__half*)&xh[r][0])[k] = __float2half(xreg);
            if (i + 2 < TT) {
                const float* xp = x + (size_t)(row0 + r) * TT * NIN + (size_t)(i + 2) * NIN + k;
                xreg = xp[0];
            }
        }
        __syncthreads();
    }

    // ---------------- FC head: y = fc2 . relu(fc1 @ h2 + b1) + b2 ----------------
    float yv = 0.f;
    if (lid < 2 * HH) {
        int r = lid >> 7, j = lid & (HH - 1);
        const float* fr = fc1w + j * HH;
        float acc = fc1b[j];
        #pragma unroll 8
        for (int k = 0; k < HH; ++k) acc = fmaf(fr[k], h1f[r][k], acc);
        yv = fmaxf(acc, 0.f) * fc2w[j];
        #pragma unroll
        for (int m = 1; m < 64; m <<= 1) yv += __shfl_xor(yv, m, 64);
    }
    __syncthreads();
    if (lid < 2 * HH && (lid & 63) == 0) pX0[0][lid >> 6] = yv;  // 4 wave sums
    __syncthreads();
    if (lid < RPB) out[row0 + lid] = pX0[0][2 * lid] + pX0[0][2 * lid + 1] + fc2b[0];
}

extern "C" void kernel_launch(void* const* d_in, const int* in_sizes, int n_in,
                              void* d_out, int out_size, void* d_ws, size_t ws_size,
                              hipStream_t stream) {
    const float* x    = (const float*)d_in[0];
    const float* Wih0 = (const float*)d_in[1];
    const float* Whh0 = (const float*)d_in[2];
    const float* bih0 = (const float*)d_in[3];
    const float* bhh0 = (const float*)d_in[4];
    const float* Wih1 = (const float*)d_in[5];
    const float* Whh1 = (const float*)d_in[6];
    const float* bih1 = (const float*)d_in[7];
    const float* bhh1 = (const float*)d_in[8];
    const float* fc1w = (const float*)d_in[9];
    const float* fc1b = (const float*)d_in[10];
    const float* fc2w = (const float*)d_in[11];
    const float* fc2b = (const float*)d_in[12];

    gru_fused<<<dim3(NWG), dim3(NTHR), 0, stream>>>(
        x, Wih0, Whh0, bih0, bhh0, Wih1, Whh1, bih1, bhh1,
        fc1w, fc1b, fc2w, fc2b, (float*)d_out);
}

// Round 3
// 2216.293 us; speedup vs baseline: 1.7988x; 1.7988x over previous
//
#include <hip/hip_runtime.h>
#include <hip/hip_fp16.h>
#include <stdint.h>

// Problem constants
#define BB   512
#define TT   1024
#define NIN  64
#define HH   128
#define GG   384      // 3*H
#define RPB  2        // batch rows per workgroup
#define NWG  (BB / RPB)   // 256 workgroups
#define NTHR (2 * GG)     // 768 threads: [0,384) layer0 gates, [384,768) layer1 gates

typedef _Float16 half2v __attribute__((ext_vector_type(2)));

__device__ __forceinline__ float fdot2(uint32_t a, uint32_t b, float c) {
    return __builtin_amdgcn_fdot2(__builtin_bit_cast(half2v, a),
                                  __builtin_bit_cast(half2v, b), c, false);
}
__device__ __forceinline__ uint32_t pack2(float a, float b) {
    half2v v; v[0] = (_Float16)a; v[1] = (_Float16)b;
    return __builtin_bit_cast(uint32_t, v);
}
__device__ __forceinline__ uint4 pack8(const float* p) {
    uint4 r;
    r.x = pack2(p[0], p[1]); r.y = pack2(p[2], p[3]);
    r.z = pack2(p[4], p[5]); r.w = pack2(p[6], p[7]);
    return r;
}
__device__ __forceinline__ float sigm(float xv)     { return 1.f / (1.f + __expf(-xv)); }
__device__ __forceinline__ float tanhfast(float xv) { return 2.f / (1.f + __expf(-2.f * xv)) - 1.f; }

// repetition macros
#define R8(M)  M(0) M(1) M(2) M(3) M(4) M(5) M(6) M(7)
#define R16(M) M(0) M(1) M(2) M(3) M(4) M(5) M(6) M(7) \
               M(8) M(9) M(10) M(11) M(12) M(13) M(14) M(15)
// 4 packed MACs: A_ += dot(W_, S_) over one uint4 (8 fp16 pairs).
// NOTE: parameter names must NOT be x/y/z/w (vector member tokens get substituted!)
#define D4(A_, W_, S_) A_ = fdot2(W_.x, S_.x, A_); A_ = fdot2(W_.y, S_.y, A_); \
                       A_ = fdot2(W_.z, S_.z, A_); A_ = fdot2(W_.w, S_.w, A_);

__global__ __launch_bounds__(NTHR, 3) void gru_fused(
    const float* __restrict__ x,
    const float* __restrict__ Wih0, const float* __restrict__ Whh0,
    const float* __restrict__ bih0, const float* __restrict__ bhh0,
    const float* __restrict__ Wih1, const float* __restrict__ Whh1,
    const float* __restrict__ bih1, const float* __restrict__ bhh1,
    const float* __restrict__ fc1w, const float* __restrict__ fc1b,
    const float* __restrict__ fc2w, const float* __restrict__ fc2b,
    float* __restrict__ out)
{
    __shared__ __align__(16) uint32_t xh[RPB][NIN / 2];   // x_t as fp16x2
    __shared__ __align__(16) uint32_t h0h[RPB][HH / 2];   // layer0 h as fp16x2
    __shared__ __align__(16) uint32_t h1h[RPB][HH / 2];   // layer1 h as fp16x2
    __shared__ float h0f[RPB][HH];                        // layer0 h fp32
    __shared__ float h1f[RPB][HH];                        // layer1 h fp32
    __shared__ float pX0[RPB][GG], pH0[RPB][GG];          // layer0 pre-acts
    __shared__ float pX1[RPB][GG], pH1[RPB][GG];          // layer1 pre-acts

    const int lid  = threadIdx.x;
    const int row0 = blockIdx.x * RPB;
    const bool is0 = (lid < GG);

    // Register-resident packed weights as NAMED SSA values (no arrays -> no scratch).
    // A0..A15: W_hh row (128 halves). B0..B15: W_ih row (layer0 uses B0..B7 only).
#define DECLW(i) uint4 A##i; uint4 B##i;
    R16(DECLW)
    float bx, bh;

    if (is0) {
        const int g = lid;
        const float* wh = Whh0 + g * HH;
        const float* wi = Wih0 + g * NIN;
#define LA0(i) A##i = pack8(wh + 8 * (i));
#define LB0(i) B##i = pack8(wi + 8 * (i));
        R16(LA0)
        R8(LB0)
        bx = bih0[g]; bh = bhh0[g];
    } else {
        const int g = lid - GG;
        const float* wh = Whh1 + g * HH;
        const float* wi = Wih1 + g * HH;
        R16(LA0)
        R16(LB0)
        bx = bih1[g]; bh = bhh1[g];
    }

    // Zero-init hidden states.
    if (lid < 2 * HH) {
        int r = lid >> 7, j = lid & (HH - 1);
        h0f[r][j] = 0.f; h1f[r][j] = 0.f;
    } else if (lid < 2 * HH + 2 * (HH / 2)) {
        int k2 = lid - 2 * HH;          // [0,128)
        int r = k2 >> 6, c = k2 & 63;
        h0h[r][c] = 0u; h1h[r][c] = 0u;
    }

    // x staging threads: lids [GG+256, GG+384). Stage x_0 now, prefetch x_1 into reg.
    float xreg = 0.f;
    if (lid >= GG + 2 * HH) {
        int j2 = lid - (GG + 2 * HH);   // [0,128)
        int r = j2 >> 6, k = j2 & 63;
        const float* xp = x + (size_t)(row0 + r) * TT * NIN + k;
        ((__half*)&xh[r][0])[k] = __float2half(xp[0]);    // t = 0
        xreg = xp[NIN];                                   // t = 1
    }
    __syncthreads();

    const uint4* xh0v  = (const uint4*)&xh[0][0];
    const uint4* xh1v  = (const uint4*)&xh[1][0];
    const uint4* h0h0v = (const uint4*)&h0h[0][0];
    const uint4* h0h1v = (const uint4*)&h0h[1][0];
    const uint4* h1h0v = (const uint4*)&h1h[0][0];
    const uint4* h1h1v = (const uint4*)&h1h[1][0];

    // Main loop. Iteration i: layer0 computes step i (i < TT);
    // layer1 computes step i-1 (i >= 1). Layer1 lags one step -> both run concurrently.
    for (int i = 0; i <= TT; ++i) {
        // ---------------- phase 1: dot products ----------------
        if (is0) {
            if (i < TT) {
                float ax0 = bx, ax1 = bx, ah0 = bh, ah1 = bh;
#define DX0(i) { uint4 s0 = xh0v[i], s1 = xh1v[i]; D4(ax0, B##i, s0) D4(ax1, B##i, s1) }
                R8(DX0)
#define DH0(i) { uint4 s0 = h0h0v[i], s1 = h0h1v[i]; D4(ah0, A##i, s0) D4(ah1, A##i, s1) }
                R16(DH0)
                pX0[0][lid] = ax0; pX0[1][lid] = ax1;
                pH0[0][lid] = ah0; pH0[1][lid] = ah1;
            }
        } else {
            if (i >= 1) {
                const int g = lid - GG;
                float ax0 = bx, ax1 = bx, ah0 = bh, ah1 = bh;
#define DL1(i) { uint4 p0 = h0h0v[i], p1 = h0h1v[i], q0 = h1h0v[i], q1 = h1h1v[i]; \
                 D4(ax0, B##i, p0) D4(ax1, B##i, p1) D4(ah0, A##i, q0) D4(ah1, A##i, q1) }
                R16(DL1)
                pX1[0][g] = ax0; pX1[1][g] = ax1;
                pH1[0][g] = ah0; pH1[1][g] = ah1;
            }
        }
        __syncthreads();

        // ---------------- phase 2: gate combine + x staging ----------------
        if (lid < 2 * HH) {                          // layer0 combine (256 threads)
            if (i < TT) {
                int r = lid >> 7, j = lid & (HH - 1);
                float sr = pX0[r][j]          + pH0[r][j];
                float sz = pX0[r][HH + j]     + pH0[r][HH + j];
                float xn = pX0[r][2 * HH + j];
                float hn = pH0[r][2 * HH + j];
                float rg = sigm(sr);
                float zg = sigm(sz);
                float ng = tanhfast(fmaf(rg, hn, xn));
                float hnew = fmaf(zg, h0f[r][j] - ng, ng);   // n + z*(h-n)
                h0f[r][j] = hnew;
                ((__half*)&h0h[r][0])[j] = __float2half(hnew);
            }
        } else if (lid >= GG && lid < GG + 2 * HH) { // layer1 combine (256 threads)
            if (i >= 1) {
                int t2 = lid - GG;
                int r = t2 >> 7, j = t2 & (HH - 1);
                float sr = pX1[r][j]          + pH1[r][j];
                float sz = pX1[r][HH + j]     + pH1[r][HH + j];
                float xn = pX1[r][2 * HH + j];
                float hn = pH1[r][2 * HH + j];
                float rg = sigm(sr);
                float zg = sigm(sz);
                float ng = tanhfast(fmaf(rg, hn, xn));
                float hnew = fmaf(zg, h1f[r][j] - ng, ng);
                h1f[r][j] = hnew;
                ((__half*)&h1h[r][0])[j] = __float2half(hnew);
            }
        } else if (lid >= GG + 2 * HH) {             // x staging (128 threads)
            int j2 = lid - (GG + 2 * HH);
            int r = j2 >> 6, k = j2 & 63;
            if (i + 1 < TT) ((__half*)&xh[r][0])[k] = __float2half(xreg);
            if (i + 2 < TT) {
                const float* xp = x + (size_t)(row0 + r) * TT * NIN + (size_t)(i + 2) * NIN + k;
                xreg = xp[0];
            }
        }
        __syncthreads();
    }

    // ---------------- FC head: y = fc2 . relu(fc1 @ h2 + b1) + b2 ----------------
    float yv = 0.f;
    if (lid < 2 * HH) {
        int r = lid >> 7, j = lid & (HH - 1);
        const float* fr = fc1w + j * HH;
        float acc = fc1b[j];
        #pragma unroll 8
        for (int k = 0; k < HH; ++k) acc = fmaf(fr[k], h1f[r][k], acc);
        yv = fmaxf(acc, 0.f) * fc2w[j];
        #pragma unroll
        for (int m = 1; m < 64; m <<= 1) yv += __shfl_xor(yv, m, 64);
    }
    __syncthreads();
    if (lid < 2 * HH && (lid & 63) == 0) pX0[0][lid >> 6] = yv;  // 4 wave sums
    __syncthreads();
    if (lid < RPB) out[row0 + lid] = pX0[0][2 * lid] + pX0[0][2 * lid + 1] + fc2b[0];
}

extern "C" void kernel_launch(void* const* d_in, const int* in_sizes, int n_in,
                              void* d_out, int out_size, void* d_ws, size_t ws_size,
                              hipStream_t stream) {
    const float* x    = (const float*)d_in[0];
    const float* Wih0 = (const float*)d_in[1];
    const float* Whh0 = (const float*)d_in[2];
    const float* bih0 = (const float*)d_in[3];
    const float* bhh0 = (const float*)d_in[4];
    const float* Wih1 = (const float*)d_in[5];
    const float* Whh1 = (const float*)d_in[6];
    const float* bih1 = (const float*)d_in[7];
    const float* bhh1 = (const float*)d_in[8];
    const float* fc1w = (const float*)d_in[9];
    const float* fc1b = (const float*)d_in[10];
    const float* fc2w = (const float*)d_in[11];
    const float* fc2b = (const float*)d_in[12];

    gru_fused<<<dim3(NWG), dim3(NTHR), 0, stream>>>(
        x, Wih0, Whh0, bih0, bhh0, Wih1, Whh1, bih1, bhh1,
        fc1w, fc1b, fc2w, fc2b, (float*)d_out);
}

// Round 4
// 2140.150 us; speedup vs baseline: 1.8628x; 1.0356x over previous
//
#include <hip/hip_runtime.h>
#include <hip/hip_fp16.h>
#include <stdint.h>

// Problem constants
#define TT   1024
#define NIN  64
#define HH   128
#define GG   384          // 3*H
#define RPB  2            // batch rows per workgroup
#define NWG  256          // 512 rows / 2
#define NTHR 768          // 12 waves

// Phase-1 role map (wave-aligned):
//   lid [  0,128)  L0X : layer0 x-dots, G=3 gates, full K=64   (24 uint4 weights)
//   lid [128,320)  L0H : layer0 h-dots, G=4 gates, half K      (32 uint4)
//   lid [320,512)  L1X : layer1 x-dots (input h0), G=4, half K (32 uint4)
//   lid [512,704)  L1H : layer1 h-dots, G=4, half K            (32 uint4)
//   lid [704,768)  stager: x -> xh double buffer
// Phase-2: lid<256 combine layer0, [256,512) combine layer1.

typedef _Float16 half2v __attribute__((ext_vector_type(2)));

__device__ __forceinline__ float fdot2(uint32_t a, uint32_t b, float c) {
    return __builtin_amdgcn_fdot2(__builtin_bit_cast(half2v, a),
                                  __builtin_bit_cast(half2v, b), c, false);
}
__device__ __forceinline__ uint32_t pack2f(float a, float b) {
    half2v v; v[0] = (_Float16)a; v[1] = (_Float16)b;
    return __builtin_bit_cast(uint32_t, v);
}
__device__ __forceinline__ uint4 pack8(const float* p) {
    uint4 r;
    r.x = pack2f(p[0], p[1]); r.y = pack2f(p[2], p[3]);
    r.z = pack2f(p[4], p[5]); r.w = pack2f(p[6], p[7]);
    return r;
}
__device__ __forceinline__ float sigm(float v)     { return 1.f / (1.f + __expf(-v)); }
__device__ __forceinline__ float tanhfast(float v) { return 2.f / (1.f + __expf(-2.f * v)) - 1.f; }

// NOTE: D4 parameter names must NOT be x/y/z/w (member tokens would be substituted).
#define D4(A_, W_, S_) A_ = fdot2(W_.x, S_.x, A_); A_ = fdot2(W_.y, S_.y, A_); \
                       A_ = fdot2(W_.z, S_.z, A_); A_ = fdot2(W_.w, S_.w, A_);

#define PK8(M_, g_) M_(g_,0) M_(g_,1) M_(g_,2) M_(g_,3) M_(g_,4) M_(g_,5) M_(g_,6) M_(g_,7)
#define R8X(M_)     M_(0) M_(1) M_(2) M_(3) M_(4) M_(5) M_(6) M_(7)
#define DWDEF(g_,k_) uint4 W##g_##_##k_;
#define LW(g_,k_)    W##g_##_##k_ = pack8(wp + (g_)*ws + (k_)*8);
// one state uint4 (8 halves) applied to gates' accumulators, both rows
#define DG(g_,k_) D4(a##g_##_0, W##g_##_##k_, s0_) D4(a##g_##_1, W##g_##_##k_, s1_)
#define SK4(k_) { uint4 s0_ = pb0[k_], s1_ = pb1[k_]; DG(0,k_) DG(1,k_) DG(2,k_) DG(3,k_) }
#define SK3(k_) { uint4 s0_ = pb0[k_], s1_ = pb1[k_]; DG(0,k_) DG(1,k_) DG(2,k_) }

__global__ __launch_bounds__(NTHR, 3) void gru_fused(
    const float* __restrict__ x,
    const float* __restrict__ Wih0, const float* __restrict__ Whh0,
    const float* __restrict__ bih0, const float* __restrict__ bhh0,
    const float* __restrict__ Wih1, const float* __restrict__ Whh1,
    const float* __restrict__ bih1, const float* __restrict__ bhh1,
    const float* __restrict__ fc1w, const float* __restrict__ fc1b,
    const float* __restrict__ fc2w, const float* __restrict__ fc2b,
    float* __restrict__ out)
{
    __shared__ __align__(16) uint32_t xh[2][RPB][NIN / 2];   // x_t fp16x2, double-buffered
    __shared__ __align__(16) uint32_t h0h[RPB][HH / 2];      // layer0 h fp16x2
    __shared__ __align__(16) uint32_t h1h[RPB][HH / 2];      // layer1 h fp16x2
    __shared__ float h0f[RPB][HH];                           // layer0 h fp32
    __shared__ float h1f[RPB][HH];                           // layer1 h fp32
    __shared__ float pX0[RPB][GG];                           // layer0 x-part (full)
    __shared__ float pH0h[2][RPB][GG];                       // layer0 h-part, K-halves
    __shared__ float pX1h[2][RPB][GG];                       // layer1 x-part, K-halves
    __shared__ float pH1h[2][RPB][GG];                       // layer1 h-part, K-halves

    const int lid  = threadIdx.x;
    const int row0 = blockIdx.x * RPB;

    // Named register-resident packed weights (max 32 uint4 = 128 VGPR).
    PK8(DWDEF,0) PK8(DWDEF,1) PK8(DWDEF,2) PK8(DWDEF,3)
    float b0 = 0.f, b1 = 0.f, b2 = 0.f, b3 = 0.f;   // acc init (bias in lo-half only)
    int gq_ = 0, kh_ = 0;
    const uint4 *pbA0 = nullptr, *pbA1 = nullptr;    // invariant state base ptrs (h-roles)
    float2 xr2 = {0.f, 0.f};                         // stager prefetch

    if (lid < 128) {                       // L0X: gates 3t..3t+2, K=64 full
        const int t = lid;
        const float* wp = Wih0 + (3 * t) * NIN; const int ws = NIN;
        PK8(LW,0) PK8(LW,1) PK8(LW,2)
        b0 = bih0[3 * t]; b1 = bih0[3 * t + 1]; b2 = bih0[3 * t + 2];
    } else if (lid < 320) {                // L0H: gates 4gq..4gq+3, K-half kh
        const int t = lid - 128; gq_ = t >> 1; kh_ = t & 1;
        const float* wp = Whh0 + (4 * gq_) * HH + kh_ * 64; const int ws = HH;
        PK8(LW,0) PK8(LW,1) PK8(LW,2) PK8(LW,3)
        if (!kh_) { b0 = bhh0[4*gq_]; b1 = bhh0[4*gq_+1]; b2 = bhh0[4*gq_+2]; b3 = bhh0[4*gq_+3]; }
        pbA0 = (const uint4*)&h0h[0][0] + kh_ * 8;
        pbA1 = (const uint4*)&h0h[1][0] + kh_ * 8;
    } else if (lid < 512) {                // L1X: input is h0
        const int t = lid - 320; gq_ = t >> 1; kh_ = t & 1;
        const float* wp = Wih1 + (4 * gq_) * HH + kh_ * 64; const int ws = HH;
        PK8(LW,0) PK8(LW,1) PK8(LW,2) PK8(LW,3)
        if (!kh_) { b0 = bih1[4*gq_]; b1 = bih1[4*gq_+1]; b2 = bih1[4*gq_+2]; b3 = bih1[4*gq_+3]; }
        pbA0 = (const uint4*)&h0h[0][0] + kh_ * 8;
        pbA1 = (const uint4*)&h0h[1][0] + kh_ * 8;
    } else if (lid < 704) {                // L1H
        const int t = lid - 512; gq_ = t >> 1; kh_ = t & 1;
        const float* wp = Whh1 + (4 * gq_) * HH + kh_ * 64; const int ws = HH;
        PK8(LW,0) PK8(LW,1) PK8(LW,2) PK8(LW,3)
        if (!kh_) { b0 = bhh1[4*gq_]; b1 = bhh1[4*gq_+1]; b2 = bhh1[4*gq_+2]; b3 = bhh1[4*gq_+3]; }
        pbA0 = (const uint4*)&h1h[0][0] + kh_ * 8;
        pbA1 = (const uint4*)&h1h[1][0] + kh_ * 8;
    } else {                               // stager: x_0 into xh[0], prefetch x_1
        const int idx = lid - 704, r = idx >> 5, c = idx & 31;
        const float* xp = x + (size_t)(row0 + r) * TT * NIN + 2 * c;
        xh[0][r][c] = pack2f(xp[0], xp[1]);
        xr2 = *(const float2*)(xp + NIN);
    }

    // Zero-init states (any threads, pre-barrier).
    if (lid < 128) {
        int r = lid >> 6, c = lid & 63;
        h0h[r][c] = 0u; h1h[r][c] = 0u;
    }
    if (lid < 256) {
        int r = lid >> 7, j = lid & 127;
        h0f[r][j] = 0.f; h1f[r][j] = 0.f;
    }
    __syncthreads();

    // Iteration i: layer0 computes step i (i<TT); layer1 computes step i-1 (i>=1).
    for (int i = 0; i <= TT; ++i) {
        // ---------------- phase 1: dots (+ x staging into the other buffer) ----
        if (lid < 128) {
            if (i < TT) {
                const uint4* pb0 = (const uint4*)&xh[i & 1][0][0];
                const uint4* pb1 = (const uint4*)&xh[i & 1][1][0];
                float a0_0 = b0, a0_1 = b0, a1_0 = b1, a1_1 = b1, a2_0 = b2, a2_1 = b2;
                R8X(SK3)
                const int g0 = 3 * lid;
                pX0[0][g0] = a0_0; pX0[0][g0+1] = a1_0; pX0[0][g0+2] = a2_0;
                pX0[1][g0] = a0_1; pX0[1][g0+1] = a1_1; pX0[1][g0+2] = a2_1;
            }
        } else if (lid < 320) {
            if (i < TT) {
                const uint4 *pb0 = pbA0, *pb1 = pbA1;
                float a0_0=b0,a0_1=b0,a1_0=b1,a1_1=b1,a2_0=b2,a2_1=b2,a3_0=b3,a3_1=b3;
                R8X(SK4)
                float4 v0 = {a0_0, a1_0, a2_0, a3_0};
                float4 v1 = {a0_1, a1_1, a2_1, a3_1};
                *(float4*)&pH0h[kh_][0][4 * gq_] = v0;
                *(float4*)&pH0h[kh_][1][4 * gq_] = v1;
            }
        } else if (lid < 512) {
            if (i >= 1) {
                const uint4 *pb0 = pbA0, *pb1 = pbA1;
                float a0_0=b0,a0_1=b0,a1_0=b1,a1_1=b1,a2_0=b2,a2_1=b2,a3_0=b3,a3_1=b3;
                R8X(SK4)
                float4 v0 = {a0_0, a1_0, a2_0, a3_0};
                float4 v1 = {a0_1, a1_1, a2_1, a3_1};
                *(float4*)&pX1h[kh_][0][4 * gq_] = v0;
                *(float4*)&pX1h[kh_][1][4 * gq_] = v1;
            }
        } else if (lid < 704) {
            if (i >= 1) {
                const uint4 *pb0 = pbA0, *pb1 = pbA1;
                float a0_0=b0,a0_1=b0,a1_0=b1,a1_1=b1,a2_0=b2,a2_1=b2,a3_0=b3,a3_1=b3;
                R8X(SK4)
                float4 v0 = {a0_0, a1_0, a2_0, a3_0};
                float4 v1 = {a0_1, a1_1, a2_1, a3_1};
                *(float4*)&pH1h[kh_][0][4 * gq_] = v0;
                *(float4*)&pH1h[kh_][1][4 * gq_] = v1;
            }
        } else {
            // stager: write x_{i+1} into the buffer phase-1 readers are NOT using.
            const int idx = lid - 704, r = idx >> 5, c = idx & 31;
            if (i + 1 < TT) xh[(i + 1) & 1][r][c] = pack2f(xr2.x, xr2.y);
            if (i + 2 < TT)
                xr2 = *(const float2*)(x + (size_t)(row0 + r) * TT * NIN
                                         + (size_t)(i + 2) * NIN + 2 * c);
        }
        __syncthreads();

        // ---------------- phase 2: gate combine ----------------
        if (lid < 256) {                       // layer0
            if (i < TT) {
                const int r = lid >> 7, j = lid & 127;
                float xr_ = pX0[r][j], xz_ = pX0[r][HH + j], xn_ = pX0[r][2*HH + j];
                float hr_ = pH0h[0][r][j]        + pH0h[1][r][j];
                float hz_ = pH0h[0][r][HH + j]   + pH0h[1][r][HH + j];
                float hn_ = pH0h[0][r][2*HH + j] + pH0h[1][r][2*HH + j];
                float rg = sigm(xr_ + hr_);
                float zg = sigm(xz_ + hz_);
                float ng = tanhfast(fmaf(rg, hn_, xn_));
                float hnew = fmaf(zg, h0f[r][j] - ng, ng);     // n + z*(h-n)
                h0f[r][j] = hnew;
                ((__half*)&h0h[r][0])[j] = __float2half(hnew);
            }
        } else if (lid < 512) {                // layer1
            if (i >= 1) {
                const int t = lid - 256, r = t >> 7, j = t & 127;
                float xr_ = pX1h[0][r][j]        + pX1h[1][r][j];
                float xz_ = pX1h[0][r][HH + j]   + pX1h[1][r][HH + j];
                float xn_ = pX1h[0][r][2*HH + j] + pX1h[1][r][2*HH + j];
                float hr_ = pH1h[0][r][j]        + pH1h[1][r][j];
                float hz_ = pH1h[0][r][HH + j]   + pH1h[1][r][HH + j];
                float hn_ = pH1h[0][r][2*HH + j] + pH1h[1][r][2*HH + j];
                float rg = sigm(xr_ + hr_);
                float zg = sigm(xz_ + hz_);
                float ng = tanhfast(fmaf(rg, hn_, xn_));
                float hnew = fmaf(zg, h1f[r][j] - ng, ng);
                h1f[r][j] = hnew;
                ((__half*)&h1h[r][0])[j] = __float2half(hnew);
            }
        }
        __syncthreads();
    }

    // ---------------- FC head: y = fc2 . relu(fc1 @ h2 + b1) + b2 ----------------
    float yv = 0.f;
    if (lid < 256) {
        const int r = lid >> 7, j = lid & 127;
        const float* fr = fc1w + j * HH;
        float acc = fc1b[j];
        #pragma unroll 8
        for (int k = 0; k < HH; ++k) acc = fmaf(fr[k], h1f[r][k], acc);
        yv = fmaxf(acc, 0.f) * fc2w[j];
        #pragma unroll
        for (int m = 1; m < 64; m <<= 1) yv += __shfl_xor(yv, m, 64);
    }
    __syncthreads();
    if (lid < 256 && (lid & 63) == 0) pX0[0][lid >> 6] = yv;   // 4 wave sums
    __syncthreads();
    if (lid < RPB) out[row0 + lid] = pX0[0][2 * lid] + pX0[0][2 * lid + 1] + fc2b[0];
}

extern "C" void kernel_launch(void* const* d_in, const int* in_sizes, int n_in,
                              void* d_out, int out_size, void* d_ws, size_t ws_size,
                              hipStream_t stream) {
    const float* x    = (const float*)d_in[0];
    const float* Wih0 = (const float*)d_in[1];
    const float* Whh0 = (const float*)d_in[2];
    const float* bih0 = (const float*)d_in[3];
    const float* bhh0 = (const float*)d_in[4];
    const float* Wih1 = (const float*)d_in[5];
    const float* Whh1 = (const float*)d_in[6];
    const float* bih1 = (const float*)d_in[7];
    const float* bhh1 = (const float*)d_in[8];
    const float* fc1w = (const float*)d_in[9];
    const float* fc1b = (const float*)d_in[10];
    const float* fc2w = (const float*)d_in[11];
    const float* fc2b = (const float*)d_in[12];

    gru_fused<<<dim3(NWG), dim3(NTHR), 0, stream>>>(
        x, Wih0, Whh0, bih0, bhh0, Wih1, Whh1, bih1, bhh1,
        fc1w, fc1b, fc2w, fc2b, (float*)d_out);
}